// Round 5
// baseline (153.135 us; speedup 1.0000x reference)
//
#include <hip/hip_runtime.h>
#include <hip/hip_fp16.h>

// Batched quantum-circuit sim. One thread PAIR (lanes 2e,2e+1) per element.
// D (7-qubit, 128 amps) state split across the pair on qubit 0: 64 half2
// VGPRs per thread -> no AGPR shuttling, 4 waves/SIMD possible, 2x waves.
// Cross-lane exchange via v_mov_dpp quad_perm (full-rate VALU, xor-1).
// ABC circuits: pass1 = lane-even A / lane-odd B in the SAME instructions
// (parity-cndmask-selected operands); pass2 = C on both lanes.

#define DEVINL __device__ __forceinline__

typedef _Float16 hv2 __attribute__((ext_vector_type(2)));

struct C2 { __half2 rr, mp; };  // complex const (r,i): rr=(r,r), mp=(-i,+i)

DEVINL C2 mkc(float re, float im) {
  C2 c; c.rr = __floats2half2_rn(re, re); c.mp = __floats2half2_rn(-im, im); return c;
}
DEVINL __half2 mkamp(float re, float im) { return __floats2half2_rn(re, im); }
DEVINL __half2 swap2(__half2 v) { return __lowhigh2highlow(v); }
DEVINL __half2 cmulc(C2 u, __half2 v) { return __hfma2(u.rr, v, __hmul2(u.mp, swap2(v))); }

DEVINL float ampsq(__half2 v, float acc) {
#if __has_builtin(__builtin_amdgcn_fdot2)
  return __builtin_amdgcn_fdot2(__builtin_bit_cast(hv2, v), __builtin_bit_cast(hv2, v), acc, false);
#else
  float2 f = __half22float2(v);
  return fmaf(f.x, f.x, fmaf(f.y, f.y, acc));
#endif
}

// cross-lane xor-1 exchange: v_mov_dpp quad_perm(1,0,3,2) -- full-rate VALU
DEVINL __half2 dpph(__half2 v) {
  int i = __builtin_bit_cast(int, v);
  i = __builtin_amdgcn_mov_dpp(i, 0xB1, 0xF, 0xF, true);
  return __builtin_bit_cast(__half2, i);
}
DEVINL float dppf(float v) {
  int i = __builtin_bit_cast(int, v);
  i = __builtin_amdgcn_mov_dpp(i, 0xB1, 0xF, 0xF, true);
  return __builtin_bit_cast(float, i);
}

DEVINL __half2 selh(bool p, __half2 a, __half2 b) {
  int ia = __builtin_bit_cast(int, a), ib = __builtin_bit_cast(int, b);
  return __builtin_bit_cast(__half2, p ? ia : ib);
}
DEVINL float self_(bool p, float a, float b) { return p ? a : b; }

constexpr int parc(int x) { x ^= x >> 4; x ^= x >> 2; x ^= x >> 1; return x & 1; }

struct c32 { float x, y; };
DEVINL c32 cmulf(c32 a, c32 b) { return { a.x*b.x - a.y*b.y, a.x*b.y + a.y*b.x }; }

// ---------------- local gates (qubit W of N-bit local space) ----------------

template<int N, int W>
DEVINL void g_ry(__half2* a, __half2 c2, __half2 s2, __half2 ns2) {
  constexpr int M = 1 << (N - 1 - W);
#pragma unroll
  for (int i = 0; i < (1 << N); ++i) if (!(i & M)) {
    const int j = i | M;
    __half2 v0 = a[i], v1 = a[j];
    a[i] = __hfma2(c2, v0, __hmul2(ns2, v1));
    a[j] = __hfma2(c2, v1, __hmul2(s2, v0));
  }
}

template<int N, int W>
DEVINL void g_u2(__half2* a, C2 u00, C2 u01, C2 u10, C2 u11) {
  constexpr int M = 1 << (N - 1 - W);
#pragma unroll
  for (int i = 0; i < (1 << N); ++i) if (!(i & M)) {
    const int j = i | M;
    __half2 v0 = a[i], v1 = a[j], v0s = swap2(v0), v1s = swap2(v1);
    a[i] = __hfma2(u00.rr, v0, __hfma2(u00.mp, v0s, __hfma2(u01.rr, v1, __hmul2(u01.mp, v1s))));
    a[j] = __hfma2(u10.rr, v0, __hfma2(u10.mp, v0s, __hfma2(u11.rr, v1, __hmul2(u11.mp, v1s))));
  }
}

template<int N, int C, int T>
DEVINL void g_cnot(__half2* a) {
  constexpr int CM = 1 << (N - 1 - C), TM = 1 << (N - 1 - T);
#pragma unroll
  for (int i = 0; i < (1 << N); ++i) if ((i & CM) && !(i & TM)) {
    const int j = i | TM;
    __half2 t = a[i]; a[i] = a[j]; a[j] = t;
  }
}

// ---------------- per-qubit coefficients (f32) ------------------------------

DEVINL void mk_u01(float ce, float se, float cp, float sp, float cf, float sf,
                   c32& u0, c32& u1) {
  u0 = cmulf({cf, -sf}, {cp * ce, sp * se});
  u1 = cmulf({cf,  sf}, {sp * ce, -cp * se});
}

// U = Rx(phi)Ry(pt)Rz(eta): A=U00, nT=U01, C=U10, D=U11 (c32)
DEVINL void mk_Uf(float ce, float se, float cp, float sp, float cf, float sf,
                  c32& A, c32& nT, c32& C, c32& D) {
  c32 z = {ce, -se}, zb = {ce, se};
  A = cmulf({cf * cp, -sf * sp}, z);
  c32 T = cmulf({cf * sp,  sf * cp}, zb);
  nT = {-T.x, -T.y};
  C = cmulf({cf * sp, -sf * cp}, z);
  D = cmulf({cf * cp,  sf * sp}, zb);
}

DEVINL void mk_U(float ce, float se, float cp, float sp, float cf, float sf,
                 C2& U00, C2& U01, C2& U10, C2& U11) {
  c32 A, nT, C, D;
  mk_Uf(ce, se, cp, sp, cf, sf, A, nT, C, D);
  U00 = mkc(A.x, A.y); U01 = mkc(nT.x, nT.y); U10 = mkc(C.x, C.y); U11 = mkc(D.x, D.y);
}

// ---------------- 4-qubit sim (16 local amps) -------------------------------

template<int N, int M>
DEVINL void build_step(__half2* a, const float* ce, const float* se, const float* cp,
                       const float* sp, const float* cf, const float* sf) {
  if constexpr (M < N) {
    c32 u0, u1; mk_u01(ce[M], se[M], cp[M], sp[M], cf[M], sf[M], u0, u1);
    C2 c0 = mkc(u0.x, u0.y), c1 = mkc(u1.x, u1.y);
#pragma unroll
    for (int j = (1 << M) - 1; j >= 0; --j) {
      __half2 s = a[j];
      a[2 * j]     = cmulc(c0, s);
      a[2 * j + 1] = cmulc(c1, s);
    }
    build_step<N, M + 1>(a, ce, se, cp, sp, cf, sf);
  }
}

template<int N, int K>
DEVINL void u_sweep(__half2* a, const float* ce, const float* se, const float* cp,
                    const float* sp, const float* cf, const float* sf) {
  if constexpr (K < N) {
    C2 U00, U01, U10, U11;
    mk_U(ce[K], se[K], cp[K], sp[K], cf[K], sf[K], U00, U01, U10, U11);
    g_u2<N, K>(a, U00, U01, U10, U11);
    u_sweep<N, K + 1>(a, ce, se, cp, sp, cf, sf);
  }
}

// angles already gathered; latent=(0,1) trash=(2,3) depth=1
DEVINL void sim4v(const float* eta, const float* pt, const float* phi,
                  const float* wv, float* z) {
  float ce[4], se[4], cp[4], sp[4], cf[4], sf[4];
#pragma unroll
  for (int k = 0; k < 4; ++k) {
    __sincosf(0.5f * eta[k], &se[k], &ce[k]);
    __sincosf(0.5f * pt[k],  &sp[k], &cp[k]);
    __sincosf(0.5f * phi[k], &sf[k], &cf[k]);
  }
  __half2 a[16];
  a[0] = mkamp(1.f, 0.f);
  build_step<4, 0>(a, ce, se, cp, sp, cf, sf);
  g_cnot<4, 0, 1>(a); g_cnot<4, 1, 2>(a); g_cnot<4, 2, 3>(a);
  u_sweep<4, 0>(a, ce, se, cp, sp, cf, sf);

  // t->l CNOT block == flip q0,q1 (mask 12) iff parity(b1,b0)
#pragma unroll
  for (int i = 0; i < 16; ++i)
    if (parc(i & 3) && !(i & 8)) { __half2 t = a[i]; a[i] = a[i ^ 12]; a[i ^ 12] = t; }

  __half2 c2[4], s2[4], ns2[4];
#pragma unroll
  for (int k = 0; k < 4; ++k) {
    float sv, cv; __sincosf(0.5f * wv[k], &sv, &cv);
    c2[k] = __floats2half2_rn(cv, cv);
    s2[k] = __floats2half2_rn(sv, sv);
    ns2[k] = __floats2half2_rn(-sv, -sv);
  }
  g_ry<4, 0>(a, c2[0], s2[0], ns2[0]); g_ry<4, 1>(a, c2[1], s2[1], ns2[1]);
  g_ry<4, 2>(a, c2[2], s2[2], ns2[2]); g_ry<4, 3>(a, c2[3], s2[3], ns2[3]);

  // l->t CNOT block == flip q2,q3 (mask 3) iff parity(b3,b2)
#pragma unroll
  for (int i = 0; i < 16; ++i)
    if (parc(i & 12) && !(i & 2)) { __half2 t = a[i]; a[i] = a[i ^ 3]; a[i ^ 3] = t; }

  float cls[4] = {0.f, 0.f, 0.f, 0.f};
#pragma unroll
  for (int i = 0; i < 16; ++i) cls[i & 3] = ampsq(a[i], cls[i & 3]);
  float z0 = 0.f, z1 = 0.f;
#pragma unroll
  for (int c = 0; c < 4; ++c) {
    z0 += (c & 2) ? -cls[c] : cls[c];
    z1 += (c & 1) ? -cls[c] : cls[c];
  }
  z[0] = z0; z[1] = z1;
}

// ---------------- 7-qubit sim, state split across lane pair on q0 -----------
// local j in [0,64): bit (5-(k-1)) of j = qubit k (k=1..6). lane parity p = q0.

template<int K>
DEVINL void d_build(__half2* a, const float* ce, const float* se, const float* cp,
                    const float* sp, const float* cf, const float* sf) {
  if constexpr (K <= 6) {
    c32 u0, u1; mk_u01(ce[K], se[K], cp[K], sp[K], cf[K], sf[K], u0, u1);
    C2 c0 = mkc(u0.x, u0.y), c1 = mkc(u1.x, u1.y);
#pragma unroll
    for (int j = (1 << (K - 1)) - 1; j >= 0; --j) {
      __half2 s = a[j];
      a[2 * j]     = cmulc(c0, s);
      a[2 * j + 1] = cmulc(c1, s);
    }
    d_build<K + 1>(a, ce, se, cp, sp, cf, sf);
  }
}

template<int K>
DEVINL void d_usweep(__half2* a, const float* ce, const float* se, const float* cp,
                     const float* sp, const float* cf, const float* sf) {
  if constexpr (K <= 6) {
    C2 U00, U01, U10, U11;
    mk_U(ce[K], se[K], cp[K], sp[K], cf[K], sf[K], U00, U01, U10, U11);
    g_u2<6, K - 1>(a, U00, U01, U10, U11);
    d_usweep<K + 1>(a, ce, se, cp, sp, cf, sf);
  }
}

template<int K>
DEVINL void d_rysweep(__half2* a, const float* cw, const float* sw) {
  if constexpr (K <= 6) {
    __half2 c2 = __floats2half2_rn(cw[K], cw[K]);
    __half2 s2 = __floats2half2_rn(sw[K], sw[K]);
    __half2 ns2 = __floats2half2_rn(-sw[K], -sw[K]);
    g_ry<6, K - 1>(a, c2, s2, ns2);
    d_rysweep<K + 1>(a, cw, sw);
  }
}

DEVINL void sim7_split(const float* r, const float* __restrict__ wD, bool p, float* z) {
  constexpr int PT[7]  = {0, 14, 30, 26, 29, 27, 17};
  constexpr int ETA[7] = {-1, 18, 40, 36, 39, 37, 21};
  constexpr int PHI[7] = {1, 22, 50, 46, 49, 47, 25};
  float ce[7], se[7], cp[7], sp[7], cf[7], sf[7];
#pragma unroll
  for (int k = 0; k < 7; ++k) {
    float e = (ETA[k] < 0) ? 0.f : r[ETA[k]];
    __sincosf(0.5f * e, &se[k], &ce[k]);
    __sincosf(0.5f * r[PT[k]],  &sp[k], &cp[k]);
    __sincosf(0.5f * r[PHI[k]], &sf[k], &cf[k]);
  }

  __half2 a[64];
  { // a[0] = forward-state q0 component for this lane's half
    c32 u0, u1; mk_u01(ce[0], se[0], cp[0], sp[0], cf[0], sf[0], u0, u1);
    a[0] = mkamp(self_(p, u1.x, u0.x), self_(p, u1.y, u0.y));
  }
  d_build<1>(a, ce, se, cp, sp, cf, sf);

  // CNOT(0,1): ctrl q0=p, tgt q1 (local bit 5): conditional local swap
#pragma unroll
  for (int j = 0; j < 32; ++j) {
    __half2 lo = a[j], hi = a[j + 32];
    a[j] = selh(p, hi, lo);
    a[j + 32] = selh(p, lo, hi);
  }
  // CNOT(k,k+1) k=1..5: local renames
  g_cnot<6, 0, 1>(a); g_cnot<6, 1, 2>(a); g_cnot<6, 2, 3>(a);
  g_cnot<6, 3, 4>(a); g_cnot<6, 4, 5>(a);

  // reverse merged-unitary sweep: q0 cross-lane, q1..q6 local
  {
    c32 A, nT, C, D;
    mk_Uf(ce[0], se[0], cp[0], sp[0], cf[0], sf[0], A, nT, C, D);
    C2 X = mkc(self_(p, D.x, A.x), self_(p, D.y, A.y));   // lane0: U00, lane1: U11
    C2 Y = mkc(self_(p, C.x, nT.x), self_(p, C.y, nT.y)); // lane0: U01, lane1: U10
#pragma unroll
    for (int j = 0; j < 64; ++j) {
      __half2 L = a[j], P = dpph(a[j]);
      __half2 t = __hfma2(X.rr, L, __hmul2(X.mp, swap2(L)));
      t = __hfma2(Y.rr, P, t);
      a[j] = __hfma2(Y.mp, swap2(P), t);
    }
  }
  d_usweep<1>(a, ce, se, cp, sp, cf, sf);

  // depth loop x4, fully unrolled
#pragma unroll
  for (int d = 0; d < 4; ++d) {
    // t->l: global i <-> i^0x78 iff parc(i&7). Splits to cross-lane pair
    // exchange {j, j^0x38} for parc(j&7)==1.
#pragma unroll
    for (int j = 0; j < 64; ++j) {
      if (parc(j & 7) && !(j & 0x20)) {
        const int k = j ^ 0x38;
        __half2 t1 = dpph(a[j]), t2 = dpph(a[k]);
        a[j] = t2; a[k] = t1;
      }
    }

    float cw[7], sw[7];
#pragma unroll
    for (int k = 0; k < 7; ++k) __sincosf(0.5f * wD[d * 7 + k], &sw[k], &cw[k]);

    // RY on q0: cross-lane. lane0: c*L - s*P ; lane1: c*L + s*P
    {
      __half2 c2 = __floats2half2_rn(cw[0], cw[0]);
      float bb = self_(p, sw[0], -sw[0]);
      __half2 b2 = __floats2half2_rn(bb, bb);
#pragma unroll
      for (int j = 0; j < 64; ++j) {
        __half2 P = dpph(a[j]);
        a[j] = __hfma2(c2, a[j], __hmul2(b2, P));
      }
    }
    d_rysweep<1>(a, cw, sw);

    // l->t: global i <-> i^7 iff parc(i&0x78) = p ^ parc(j&0x38): local
    // conditional swaps with compile-time polarity.
#pragma unroll
    for (int j = 0; j < 64; ++j) {
      if (!(j & 4)) {
        const int k = j ^ 7;
        __half2 lo = a[j], hi = a[k];
        if (parc(j & 0x38)) {  // swap iff p==0
          a[j] = selh(p, lo, hi);
          a[k] = selh(p, hi, lo);
        } else {               // swap iff p==1
          a[j] = selh(p, hi, lo);
          a[k] = selh(p, lo, hi);
        }
      }
    }
  }

  // readout: class = local j&7 (= global q4,q5,q6)
  float cls[8] = {0.f, 0.f, 0.f, 0.f, 0.f, 0.f, 0.f, 0.f};
#pragma unroll
  for (int j = 0; j < 64; ++j) cls[j & 7] = ampsq(a[j], cls[j & 7]);
  float z4 = 0.f, z5 = 0.f, z6 = 0.f;
#pragma unroll
  for (int c = 0; c < 8; ++c) {
    z4 += (c & 4) ? -cls[c] : cls[c];
    z5 += (c & 2) ? -cls[c] : cls[c];
    z6 += (c & 1) ? -cls[c] : cls[c];
  }
  // cross-lane total
  z[0] = z4 + dppf(z4);
  z[1] = z5 + dppf(z5);
  z[2] = z6 + dppf(z6);
}

// ---------------- kernel -----------------------------------------------------

__global__ void __launch_bounds__(256, 3)
k_all(const float* __restrict__ x,
      const float* __restrict__ wA, const float* __restrict__ wB,
      const float* __restrict__ wC, const float* __restrict__ wD,
      float* __restrict__ out, int B) {
  const int tid = threadIdx.x;
  const bool p = (tid & 1);
  const int e = blockIdx.x * 128 + (tid >> 1);
  if (e >= B) return;

  float r[56];
  const float4* row4 = (const float4*)(x + (size_t)e * 56);
#pragma unroll
  for (int i = 0; i < 14; ++i) {
    float4 v = row4[i];
    r[4 * i] = v.x; r[4 * i + 1] = v.y; r[4 * i + 2] = v.z; r[4 * i + 3] = v.w;
  }
  float* op = out + (size_t)e * 9;

  { // pass 1: lane-even = circuit A, lane-odd = circuit B (same instructions)
    constexpr int PTA[4] = {5, 4, 35, 34}, ETAA[4] = {9, 8, 45, 44}, PHIA[4] = {13, 12, 55, 54};
    constexpr int PTB[4] = {3, 33, 31, 2}, ETAB[4] = {7, 43, 41, 6}, PHIB[4] = {11, 53, 51, 10};
    float pe[4], pp[4], pf[4], wv[4];
#pragma unroll
    for (int k = 0; k < 4; ++k) {
      pe[k] = self_(p, r[ETAB[k]], r[ETAA[k]]);
      pp[k] = self_(p, r[PTB[k]],  r[PTA[k]]);
      pf[k] = self_(p, r[PHIB[k]], r[PHIA[k]]);
      wv[k] = self_(p, wB[k], wA[k]);
    }
    float z2[2];
    sim4v(pe, pp, pf, wv, z2);
    const int base = p ? 2 : 0;
    op[base] = z2[0]; op[base + 1] = z2[1];
  }

  { // pass 2: circuit C on both lanes (lane-even writes)
    constexpr int PTC[4] = {28, 32, 15, 16}, ETAC[4] = {38, 42, 19, 20}, PHIC[4] = {48, 52, 23, 24};
    float pe[4], pp[4], pf[4], wv[4];
#pragma unroll
    for (int k = 0; k < 4; ++k) {
      pe[k] = r[ETAC[k]]; pp[k] = r[PTC[k]]; pf[k] = r[PHIC[k]]; wv[k] = wC[k];
    }
    float z2[2];
    sim4v(pe, pp, pf, wv, z2);
    if (!p) { op[4] = z2[0]; op[5] = z2[1]; }
  }

  { // D: pair-split 7-qubit sim (lane-odd writes)
    float z3[3];
    sim7_split(r, wD, p, z3);
    if (p) { op[6] = z3[0]; op[7] = z3[1]; op[8] = z3[2]; }
  }
}

// ---------------- launch ----------------------------------------------------

extern "C" void kernel_launch(void* const* d_in, const int* in_sizes, int n_in,
                              void* d_out, int out_size, void* d_ws, size_t ws_size,
                              hipStream_t stream) {
  const float* x  = (const float*)d_in[0];
  const float* wA = (const float*)d_in[1];
  const float* wB = (const float*)d_in[2];
  const float* wC = (const float*)d_in[3];
  const float* wD = (const float*)d_in[4];
  float* out = (float*)d_out;
  const int B = in_sizes[0] / 56;
  const int grid = (B + 127) / 128;  // 128 elements per 256-thread block
  k_all<<<grid, 256, 0, stream>>>(x, wA, wB, wC, wD, out, B);
}

// Round 6
// 139.119 us; speedup vs baseline: 1.1007x; 1.1007x over previous
//
#include <hip/hip_runtime.h>
#include <hip/hip_fp16.h>

// Batched quantum-circuit sim, ONE fused kernel, one thread per element.
// State: __half2 (re,im) per amplitude -> v_pk_fma_f16 gates.
// KEY FIX vs R3: __launch_bounds__(256,1). The (256,2) bound capped the
// unified reg budget at 256/wave -> allocator split 128 arch VGPR + 128 AGPR
// and shuttled the state through v_accvgpr_read/write on every gate (~2x
// instruction bloat). Grid is occupancy-limited to 2 waves/SIMD anyway
// (131072 threads = 2048 waves / 1024 SIMDs), so the cap bought nothing.
// Depth loop fully unrolled: parity permutations = register renames.

#define DEVINL __device__ __forceinline__

typedef _Float16 hv2 __attribute__((ext_vector_type(2)));

struct C2 { __half2 rr, mp; };  // complex const (r,i): rr=(r,r), mp=(-i,+i)

DEVINL C2 mkc(float re, float im) {
  C2 c; c.rr = __floats2half2_rn(re, re); c.mp = __floats2half2_rn(-im, im); return c;
}
DEVINL __half2 mkamp(float re, float im) { return __floats2half2_rn(re, im); }
DEVINL __half2 swap2(__half2 v) { return __lowhigh2highlow(v); }
// (const u) * (amp v):  (r*vr - i*vi, r*vi + i*vr)
DEVINL __half2 cmulc(C2 u, __half2 v) { return __hfma2(u.rr, v, __hmul2(u.mp, swap2(v))); }

DEVINL float ampsq(__half2 v, float acc) {
#if __has_builtin(__builtin_amdgcn_fdot2)
  return __builtin_amdgcn_fdot2(__builtin_bit_cast(hv2, v), __builtin_bit_cast(hv2, v), acc, false);
#else
  float2 f = __half22float2(v);
  return fmaf(f.x, f.x, fmaf(f.y, f.y, acc));
#endif
}

constexpr int parc(int x) { x ^= x >> 4; x ^= x >> 2; x ^= x >> 1; return x & 1; }

struct c32 { float x, y; };
DEVINL c32 cmulf(c32 a, c32 b) { return { a.x*b.x - a.y*b.y, a.x*b.y + a.y*b.x }; }

// ---------------- gates (qubit W of N; mask = 1<<(N-1-W)) -------------------

template<int N, int W>
DEVINL void g_ry(__half2* a, __half2 c2, __half2 s2, __half2 ns2) {
  constexpr int M = 1 << (N - 1 - W);
#pragma unroll
  for (int i = 0; i < (1 << N); ++i) if (!(i & M)) {
    const int j = i | M;
    __half2 v0 = a[i], v1 = a[j];
    a[i] = __hfma2(c2, v0, __hmul2(ns2, v1));
    a[j] = __hfma2(c2, v1, __hmul2(s2, v0));
  }
}

template<int N, int W>
DEVINL void g_u2(__half2* a, C2 u00, C2 u01, C2 u10, C2 u11) {
  constexpr int M = 1 << (N - 1 - W);
#pragma unroll
  for (int i = 0; i < (1 << N); ++i) if (!(i & M)) {
    const int j = i | M;
    __half2 v0 = a[i], v1 = a[j], v0s = swap2(v0), v1s = swap2(v1);
    a[i] = __hfma2(u00.rr, v0, __hfma2(u00.mp, v0s, __hfma2(u01.rr, v1, __hmul2(u01.mp, v1s))));
    a[j] = __hfma2(u10.rr, v0, __hfma2(u10.mp, v0s, __hfma2(u11.rr, v1, __hmul2(u11.mp, v1s))));
  }
}

template<int N, int C, int T>
DEVINL void g_cnot(__half2* a) {
  constexpr int CM = 1 << (N - 1 - C), TM = 1 << (N - 1 - T);
#pragma unroll
  for (int i = 0; i < (1 << N); ++i) if ((i & CM) && !(i & TM)) {
    const int j = i | TM;
    __half2 t = a[i]; a[i] = a[j]; a[j] = t;
  }
}

template<int N, int K>
DEVINL void chain_cnot(__half2* a) {
  if constexpr (K < N - 1) { g_cnot<N, K, K + 1>(a); chain_cnot<N, K + 1>(a); }
}

// ---------------- per-qubit coefficients (f32) ------------------------------
// forward: u = Rz(phi)Ry(pt)Rx(eta)|0>;  reverse merged: U = Rx(phi)Ry(pt)Rz(eta)

DEVINL void mk_u01(float ce, float se, float cp, float sp, float cf, float sf,
                   c32& u0, c32& u1) {
  u0 = cmulf({cf, -sf}, {cp * ce, sp * se});
  u1 = cmulf({cf,  sf}, {sp * ce, -cp * se});
}

DEVINL void mk_U(float ce, float se, float cp, float sp, float cf, float sf,
                 C2& U00, C2& U01, C2& U10, C2& U11) {
  c32 z = {ce, -se}, zb = {ce, se};
  c32 A = cmulf({cf * cp, -sf * sp}, z);
  c32 T = cmulf({cf * sp,  sf * cp}, zb);
  c32 Cc = cmulf({cf * sp, -sf * cp}, z);
  c32 D = cmulf({cf * cp,  sf * sp}, zb);
  U00 = mkc(A.x, A.y); U01 = mkc(-T.x, -T.y); U10 = mkc(Cc.x, Cc.y); U11 = mkc(D.x, D.y);
}

// product state build by doubling (a[0] must be (1,0) on entry)
template<int N, int M>
DEVINL void build_step(__half2* a, const float* ce, const float* se, const float* cp,
                       const float* sp, const float* cf, const float* sf) {
  if constexpr (M < N) {
    c32 u0, u1; mk_u01(ce[M], se[M], cp[M], sp[M], cf[M], sf[M], u0, u1);
    C2 c0 = mkc(u0.x, u0.y), c1 = mkc(u1.x, u1.y);
#pragma unroll
    for (int j = (1 << M) - 1; j >= 0; --j) {
      __half2 s = a[j];
      a[2 * j]     = cmulc(c0, s);
      a[2 * j + 1] = cmulc(c1, s);
    }
    build_step<N, M + 1>(a, ce, se, cp, sp, cf, sf);
  }
}

template<int N, int K>
DEVINL void u_sweep(__half2* a, const float* ce, const float* se, const float* cp,
                    const float* sp, const float* cf, const float* sf) {
  if constexpr (K < N) {
    C2 U00, U01, U10, U11;
    mk_U(ce[K], se[K], cp[K], sp[K], cf[K], sf[K], U00, U01, U10, U11);
    g_u2<N, K>(a, U00, U01, U10, U11);
    u_sweep<N, K + 1>(a, ce, se, cp, sp, cf, sf);
  }
}

template<int N, int K>
DEVINL void ry_sweep(__half2* a, const __half2* c2, const __half2* s2, const __half2* ns2) {
  if constexpr (K < N) {
    g_ry<N, K>(a, c2[K], s2[K], ns2[K]);
    ry_sweep<N, K + 1>(a, c2, s2, ns2);
  }
}

// ---------------- 4-qubit block I: latent=(0,1) trash=(2,3) depth=1 ---------

template<int I>
DEVINL void sim4h(const float* r, const float* __restrict__ w, float* z) {
  constexpr int PT[3][4]  = {{5, 4, 35, 34}, {3, 33, 31, 2}, {28, 32, 15, 16}};
  constexpr int ETA[3][4] = {{9, 8, 45, 44}, {7, 43, 41, 6}, {38, 42, 19, 20}};
  constexpr int PHI[3][4] = {{13, 12, 55, 54}, {11, 53, 51, 10}, {48, 52, 23, 24}};
  float ce[4], se[4], cp[4], sp[4], cf[4], sf[4];
#pragma unroll
  for (int k = 0; k < 4; ++k) {
    __sincosf(0.5f * r[ETA[I][k]], &se[k], &ce[k]);
    __sincosf(0.5f * r[PT[I][k]],  &sp[k], &cp[k]);
    __sincosf(0.5f * r[PHI[I][k]], &sf[k], &cf[k]);
  }
  __half2 a[16];
  a[0] = mkamp(1.f, 0.f);
  build_step<4, 0>(a, ce, se, cp, sp, cf, sf);
  chain_cnot<4, 0>(a);
  u_sweep<4, 0>(a, ce, se, cp, sp, cf, sf);

  // t->l CNOT block == flip q0,q1 (mask 12) iff parity(b2,b3) (i&3)
#pragma unroll
  for (int i = 0; i < 16; ++i)
    if (parc(i & 3) && !(i & 8)) { __half2 t = a[i]; a[i] = a[i ^ 12]; a[i ^ 12] = t; }

  __half2 c2[4], s2[4], ns2[4];
#pragma unroll
  for (int k = 0; k < 4; ++k) {
    float sv, cv; __sincosf(0.5f * w[k], &sv, &cv);
    c2[k] = __floats2half2_rn(cv, cv);
    s2[k] = __floats2half2_rn(sv, sv);
    ns2[k] = __floats2half2_rn(-sv, -sv);
  }
  ry_sweep<4, 0>(a, c2, s2, ns2);

  // l->t CNOT block == flip q2,q3 (mask 3) iff parity(b0,b1) (i&12)
#pragma unroll
  for (int i = 0; i < 16; ++i)
    if (parc(i & 12) && !(i & 2)) { __half2 t = a[i]; a[i] = a[i ^ 3]; a[i ^ 3] = t; }

  float cls[4] = {0.f, 0.f, 0.f, 0.f};
#pragma unroll
  for (int i = 0; i < 16; ++i) cls[i & 3] = ampsq(a[i], cls[i & 3]);
  float z0 = 0.f, z1 = 0.f;
#pragma unroll
  for (int c = 0; c < 4; ++c) {
    z0 += (c & 2) ? -cls[c] : cls[c];
    z1 += (c & 1) ? -cls[c] : cls[c];
  }
  z[0] = z0; z[1] = z1;
}

// ---------------- 7-qubit block: latent=(0..3) trash=(4,5,6) depth=4 --------

DEVINL void sim7h(const float* r, const float* __restrict__ wD, float* z) {
  constexpr int PT[7]  = {0, 14, 30, 26, 29, 27, 17};
  constexpr int ETA[7] = {-1, 18, 40, 36, 39, 37, 21};  // -1 -> zeros (None)
  constexpr int PHI[7] = {1, 22, 50, 46, 49, 47, 25};
  float ce[7], se[7], cp[7], sp[7], cf[7], sf[7];
#pragma unroll
  for (int k = 0; k < 7; ++k) {
    float e = (ETA[k] < 0) ? 0.f : r[ETA[k]];
    __sincosf(0.5f * e, &se[k], &ce[k]);
    __sincosf(0.5f * r[PT[k]],  &sp[k], &cp[k]);
    __sincosf(0.5f * r[PHI[k]], &sf[k], &cf[k]);
  }
  __half2 a[128];
  a[0] = mkamp(1.f, 0.f);
  build_step<7, 0>(a, ce, se, cp, sp, cf, sf);
  chain_cnot<7, 0>(a);
  u_sweep<7, 0>(a, ce, se, cp, sp, cf, sf);

  // depth loop FULLY UNROLLED: parity permutations become register renames
#pragma unroll
  for (int d = 0; d < 4; ++d) {
    // t->l block == flip q0..q3 (mask 0x78) iff parity(b4,b5,b6) (i&7)
#pragma unroll
    for (int i = 0; i < 128; ++i)
      if (parc(i & 7) && !(i & 64)) { __half2 t = a[i]; a[i] = a[i ^ 0x78]; a[i ^ 0x78] = t; }

    __half2 c2[7], s2[7], ns2[7];
#pragma unroll
    for (int k = 0; k < 7; ++k) {
      float sv, cv; __sincosf(0.5f * wD[d * 7 + k], &sv, &cv);
      c2[k] = __floats2half2_rn(cv, cv);
      s2[k] = __floats2half2_rn(sv, sv);
      ns2[k] = __floats2half2_rn(-sv, -sv);
    }
    ry_sweep<7, 0>(a, c2, s2, ns2);

    // l->t block == flip q4..q6 (mask 7) iff parity(b0..b3) (i&0x78)
#pragma unroll
    for (int i = 0; i < 128; ++i)
      if (parc(i & 0x78) && !(i & 4)) { __half2 t = a[i]; a[i] = a[i ^ 7]; a[i ^ 7] = t; }
  }

  float cls[8] = {0.f, 0.f, 0.f, 0.f, 0.f, 0.f, 0.f, 0.f};
#pragma unroll
  for (int i = 0; i < 128; ++i) cls[i & 7] = ampsq(a[i], cls[i & 7]);
  float z4 = 0.f, z5 = 0.f, z6 = 0.f;
#pragma unroll
  for (int c = 0; c < 8; ++c) {
    z4 += (c & 4) ? -cls[c] : cls[c];
    z5 += (c & 2) ? -cls[c] : cls[c];
    z6 += (c & 1) ? -cls[c] : cls[c];
  }
  z[0] = z4; z[1] = z5; z[2] = z6;
}

// ---------------- fused kernel ----------------------------------------------

__global__ void __launch_bounds__(256, 1)
k_all(const float* __restrict__ x,
      const float* __restrict__ wA, const float* __restrict__ wB,
      const float* __restrict__ wC, const float* __restrict__ wD,
      float* __restrict__ out, int B) {
  const int b = blockIdx.x * blockDim.x + threadIdx.x;
  if (b >= B) return;

  // whole row, coalesced 16B loads (row stride 224B is 16B-aligned)
  float r[56];
  const float4* row4 = (const float4*)(x + (size_t)b * 56);
#pragma unroll
  for (int i = 0; i < 14; ++i) {
    float4 v = row4[i];
    r[4 * i] = v.x; r[4 * i + 1] = v.y; r[4 * i + 2] = v.z; r[4 * i + 3] = v.w;
  }

  float* op = out + (size_t)b * 9;

  // ABC first (small state); their 36 row-columns die before D's 128-amp
  // state phase begins (D uses a disjoint set of 20 columns).
  float o[6];
  sim4h<0>(r, wA, &o[0]);
  sim4h<1>(r, wB, &o[2]);
  sim4h<2>(r, wC, &o[4]);
#pragma unroll
  for (int i = 0; i < 6; ++i) op[i] = o[i];

  float z[3];
  sim7h(r, wD, z);
  op[6] = z[0]; op[7] = z[1]; op[8] = z[2];
}

// ---------------- launch ----------------------------------------------------

extern "C" void kernel_launch(void* const* d_in, const int* in_sizes, int n_in,
                              void* d_out, int out_size, void* d_ws, size_t ws_size,
                              hipStream_t stream) {
  const float* x  = (const float*)d_in[0];
  const float* wA = (const float*)d_in[1];
  const float* wB = (const float*)d_in[2];
  const float* wC = (const float*)d_in[3];
  const float* wD = (const float*)d_in[4];
  float* out = (float*)d_out;
  const int B = in_sizes[0] / 56;
  const int threads = 256;
  const int grid = (B + threads - 1) / threads;
  k_all<<<grid, threads, 0, stream>>>(x, wA, wB, wC, wD, out, B);
}

// Round 8
// 128.751 us; speedup vs baseline: 1.1894x; 1.0805x over previous
//
#include <hip/hip_runtime.h>

// Batched quantum-circuit sim, one fused kernel, one thread per element.
// State: _Float16x2 (re,im)/amp -> v_pk_fma_f16. Native hv2 + shufflevector
// (op_sel folding), SU(2) coefficient form (U11=conj(U00), U01=-conj(U10)),
// weight sincos hoisted to a setup kernel (uniform loads).
// R7 FIX: coefficient packs use ROUND-NEAREST (scalar casts + v_pack), not
// cvt_pkrtz. RTZ's toward-zero bias accumulated linearly over ~30
// multiplicative coefficient applications -> absmax 0.047 (R6 fail).
// Config = best measured: rolled depth loop + __launch_bounds__(256,2).

#define DEVINL __device__ __forceinline__

typedef _Float16 h2 __attribute__((ext_vector_type(2)));

DEVINL h2 hswap(h2 v) { return __builtin_shufflevector(v, v, 1, 0); }
DEVINL h2 ffma(h2 a, h2 b, h2 c) { return __builtin_elementwise_fma(a, b, c); }
// round-nearest pack (v_cvt_f16_f32 x2 + v_pack_b32_f16); do NOT use
// cvt_pkrtz here -- biased rounding compounds across the gate chain.
DEVINL h2 cvt2(float a, float b) {
  h2 r; r.x = (_Float16)a; r.y = (_Float16)b; return r;
}
DEVINL h2 uash2(unsigned u) { return __builtin_bit_cast(h2, u); }

DEVINL float ampsq(h2 v, float acc) {
#if __has_builtin(__builtin_amdgcn_fdot2)
  return __builtin_amdgcn_fdot2(v, v, acc, false);
#else
  float x = (float)v.x, y = (float)v.y;
  return fmaf(x, x, fmaf(y, y, acc));
#endif
}

struct CC { h2 rr, mp; };  // complex const (r,i): rr=(r,r), mp=(-i,+i)
DEVINL CC mkcc(float re, float im) { return { cvt2(re, re), cvt2(-im, im) }; }
// (const u) * (amp v)
DEVINL h2 cmulc(CC u, h2 v) { return ffma(u.rr, v, u.mp * hswap(v)); }

constexpr int parc(int x) { x ^= x >> 4; x ^= x >> 2; x ^= x >> 1; return x & 1; }

struct c32 { float x, y; };
DEVINL c32 cmulf(c32 a, c32 b) { return { a.x*b.x - a.y*b.y, a.x*b.y + a.y*b.x }; }

// ---------------- gates (qubit W of N; mask = 1<<(N-1-W)) -------------------

template<int N, int W>
DEVINL void g_ry(h2* a, h2 c2, h2 s2) {
  constexpr int M = 1 << (N - 1 - W);
#pragma unroll
  for (int i = 0; i < (1 << N); ++i) if (!(i & M)) {
    const int j = i | M;
    h2 v0 = a[i], v1 = a[j];
    a[i] = ffma(c2, v0, -(s2 * v1));
    a[j] = ffma(s2, v0, c2 * v1);
  }
}

// SU(2) unitary: U = [[A, -conj(C)], [C, conj(A)]]
template<int N, int W>
DEVINL void g_u2(h2* a, h2 Arr, h2 Amp, h2 Crr, h2 Cmp) {
  constexpr int M = 1 << (N - 1 - W);
#pragma unroll
  for (int i = 0; i < (1 << N); ++i) if (!(i & M)) {
    const int j = i | M;
    h2 v0 = a[i], v1 = a[j], s0 = hswap(v0), s1 = hswap(v1);
    // o0 = A*v0 - conj(C)*v1 ; o1 = C*v0 + conj(A)*v1
    h2 o0 = Arr * v0; o0 = ffma(Amp, s0, o0); o0 = ffma(Cmp, s1, o0); o0 = ffma(-Crr, v1, o0);
    h2 o1 = Crr * v0; o1 = ffma(Cmp, s0, o1); o1 = ffma(-Amp, s1, o1); o1 = ffma(Arr, v1, o1);
    a[i] = o0; a[j] = o1;
  }
}

template<int N, int C, int T>
DEVINL void g_cnot(h2* a) {
  constexpr int CM = 1 << (N - 1 - C), TM = 1 << (N - 1 - T);
#pragma unroll
  for (int i = 0; i < (1 << N); ++i) if ((i & CM) && !(i & TM)) {
    const int j = i | TM;
    h2 t = a[i]; a[i] = a[j]; a[j] = t;
  }
}

template<int N, int K>
DEVINL void chain_cnot(h2* a) {
  if constexpr (K < N - 1) { g_cnot<N, K, K + 1>(a); chain_cnot<N, K + 1>(a); }
}

// ---------------- per-qubit coefficients (f32) ------------------------------
// forward: u = Rz(phi)Ry(pt)Rx(eta)|0>;  reverse merged: U = Rx(phi)Ry(pt)Rz(eta)

DEVINL void mk_u01(float ce, float se, float cp, float sp, float cf, float sf,
                   c32& u0, c32& u1) {
  u0 = cmulf({cf, -sf}, {cp * ce, sp * se});
  u1 = cmulf({cf,  sf}, {sp * ce, -cp * se});
}

// A = U00, C = U10 of the SU(2) merged unitary
DEVINL void mk_AC(float ce, float se, float cp, float sp, float cf, float sf,
                  c32& A, c32& C) {
  c32 z = {ce, -se};
  A = cmulf({cf * cp, -sf * sp}, z);
  C = cmulf({cf * sp, -sf * cp}, z);
}

// product state build by doubling (a[0] must be (1,0) on entry)
template<int N, int M>
DEVINL void build_step(h2* a, const float* ce, const float* se, const float* cp,
                       const float* sp, const float* cf, const float* sf) {
  if constexpr (M < N) {
    c32 u0, u1; mk_u01(ce[M], se[M], cp[M], sp[M], cf[M], sf[M], u0, u1);
    CC c0 = mkcc(u0.x, u0.y), c1 = mkcc(u1.x, u1.y);
#pragma unroll
    for (int j = (1 << M) - 1; j >= 0; --j) {
      h2 s = a[j];
      a[2 * j]     = cmulc(c0, s);
      a[2 * j + 1] = cmulc(c1, s);
    }
    build_step<N, M + 1>(a, ce, se, cp, sp, cf, sf);
  }
}

template<int N, int K>
DEVINL void u_sweep(h2* a, const float* ce, const float* se, const float* cp,
                    const float* sp, const float* cf, const float* sf) {
  if constexpr (K < N) {
    c32 A, C;
    mk_AC(ce[K], se[K], cp[K], sp[K], cf[K], sf[K], A, C);
    g_u2<N, K>(a, cvt2(A.x, A.x), cvt2(-A.y, A.y), cvt2(C.x, C.x), cvt2(-C.y, C.y));
    u_sweep<N, K + 1>(a, ce, se, cp, sp, cf, sf);
  }
}

// RY layer from precomputed packed weight table (uniform loads)
template<int N, int K>
DEVINL void ry_sweep_wt(h2* a, const uint2* __restrict__ w) {
  if constexpr (K < N) {
    uint2 q = w[K];
    g_ry<N, K>(a, uash2(q.x), uash2(q.y));
    ry_sweep_wt<N, K + 1>(a, w);
  }
}

// ---------------- 4-qubit block I: latent=(0,1) trash=(2,3) depth=1 ---------

template<int I>
DEVINL void sim4h(const float* r, const uint2* __restrict__ wt, float* z) {
  constexpr int PT[3][4]  = {{5, 4, 35, 34}, {3, 33, 31, 2}, {28, 32, 15, 16}};
  constexpr int ETA[3][4] = {{9, 8, 45, 44}, {7, 43, 41, 6}, {38, 42, 19, 20}};
  constexpr int PHI[3][4] = {{13, 12, 55, 54}, {11, 53, 51, 10}, {48, 52, 23, 24}};
  float ce[4], se[4], cp[4], sp[4], cf[4], sf[4];
#pragma unroll
  for (int k = 0; k < 4; ++k) {
    __sincosf(0.5f * r[ETA[I][k]], &se[k], &ce[k]);
    __sincosf(0.5f * r[PT[I][k]],  &sp[k], &cp[k]);
    __sincosf(0.5f * r[PHI[I][k]], &sf[k], &cf[k]);
  }
  h2 a[16];
  a[0] = cvt2(1.f, 0.f);
  build_step<4, 0>(a, ce, se, cp, sp, cf, sf);
  chain_cnot<4, 0>(a);
  u_sweep<4, 0>(a, ce, se, cp, sp, cf, sf);

  // t->l CNOT block == flip q0,q1 (mask 12) iff parity(b2,b3) (i&3)
#pragma unroll
  for (int i = 0; i < 16; ++i)
    if (parc(i & 3) && !(i & 8)) { h2 t = a[i]; a[i] = a[i ^ 12]; a[i ^ 12] = t; }

  ry_sweep_wt<4, 0>(a, wt + 4 * I);

  // l->t CNOT block == flip q2,q3 (mask 3) iff parity(b0,b1) (i&12)
#pragma unroll
  for (int i = 0; i < 16; ++i)
    if (parc(i & 12) && !(i & 2)) { h2 t = a[i]; a[i] = a[i ^ 3]; a[i ^ 3] = t; }

  float cls[4] = {0.f, 0.f, 0.f, 0.f};
#pragma unroll
  for (int i = 0; i < 16; ++i) cls[i & 3] = ampsq(a[i], cls[i & 3]);
  float z0 = 0.f, z1 = 0.f;
#pragma unroll
  for (int c = 0; c < 4; ++c) {
    z0 += (c & 2) ? -cls[c] : cls[c];
    z1 += (c & 1) ? -cls[c] : cls[c];
  }
  z[0] = z0; z[1] = z1;
}

// ---------------- 7-qubit block: latent=(0..3) trash=(4,5,6) depth=4 --------

DEVINL void sim7h(const float* r, const uint2* __restrict__ wtD, float* z) {
  constexpr int PT[7]  = {0, 14, 30, 26, 29, 27, 17};
  constexpr int ETA[7] = {-1, 18, 40, 36, 39, 37, 21};  // -1 -> zeros (None)
  constexpr int PHI[7] = {1, 22, 50, 46, 49, 47, 25};
  float ce[7], se[7], cp[7], sp[7], cf[7], sf[7];
#pragma unroll
  for (int k = 0; k < 7; ++k) {
    float e = (ETA[k] < 0) ? 0.f : r[ETA[k]];
    __sincosf(0.5f * e, &se[k], &ce[k]);
    __sincosf(0.5f * r[PT[k]],  &sp[k], &cp[k]);
    __sincosf(0.5f * r[PHI[k]], &sf[k], &cf[k]);
  }
  h2 a[128];
  a[0] = cvt2(1.f, 0.f);
  build_step<7, 0>(a, ce, se, cp, sp, cf, sf);
  chain_cnot<7, 0>(a);
  u_sweep<7, 0>(a, ce, se, cp, sp, cf, sf);

  // depth loop kept rolled (best measured: code stays hot in L1I)
#pragma unroll 1
  for (int d = 0; d < 4; ++d) {
    // t->l block == flip q0..q3 (mask 0x78) iff parity(b4,b5,b6) (i&7)
#pragma unroll
    for (int i = 0; i < 128; ++i)
      if (parc(i & 7) && !(i & 64)) { h2 t = a[i]; a[i] = a[i ^ 0x78]; a[i ^ 0x78] = t; }

    ry_sweep_wt<7, 0>(a, wtD + d * 7);

    // l->t block == flip q4..q6 (mask 7) iff parity(b0..b3) (i&0x78)
#pragma unroll
    for (int i = 0; i < 128; ++i)
      if (parc(i & 0x78) && !(i & 4)) { h2 t = a[i]; a[i] = a[i ^ 7]; a[i ^ 7] = t; }
  }

  float cls[8] = {0.f, 0.f, 0.f, 0.f, 0.f, 0.f, 0.f, 0.f};
#pragma unroll
  for (int i = 0; i < 128; ++i) cls[i & 7] = ampsq(a[i], cls[i & 7]);
  float z4 = 0.f, z5 = 0.f, z6 = 0.f;
#pragma unroll
  for (int c = 0; c < 8; ++c) {
    z4 += (c & 4) ? -cls[c] : cls[c];
    z5 += (c & 2) ? -cls[c] : cls[c];
    z6 += (c & 1) ? -cls[c] : cls[c];
  }
  z[0] = z4; z[1] = z5; z[2] = z6;
}

// ---------------- kernels ----------------------------------------------------

// setup: pack cos/sin(w/2) of all 40 weights as half2 broadcasts into d_ws.
// layout: wt[i] = { (c,c) as u32, (s,s) as u32 }; A:0-3 B:4-7 C:8-11 D:12-39.
__global__ void k_wt(const float* __restrict__ wA, const float* __restrict__ wB,
                     const float* __restrict__ wC, const float* __restrict__ wD,
                     uint2* __restrict__ wt) {
  const int t = threadIdx.x;
  if (t >= 40) return;
  float w = (t < 4) ? wA[t] : (t < 8) ? wB[t - 4] : (t < 12) ? wC[t - 8] : wD[t - 12];
  float sv, cv; __sincosf(0.5f * w, &sv, &cv);
  wt[t] = make_uint2(__builtin_bit_cast(unsigned, cvt2(cv, cv)),
                     __builtin_bit_cast(unsigned, cvt2(sv, sv)));
}

__global__ void __launch_bounds__(256, 2)
k_all(const float* __restrict__ x, const uint2* __restrict__ wt,
      float* __restrict__ out, int B) {
  const int b = blockIdx.x * blockDim.x + threadIdx.x;
  if (b >= B) return;

  // whole row, coalesced 16B loads (row stride 224B is 16B-aligned)
  float r[56];
  const float4* row4 = (const float4*)(x + (size_t)b * 56);
#pragma unroll
  for (int i = 0; i < 14; ++i) {
    float4 v = row4[i];
    r[4 * i] = v.x; r[4 * i + 1] = v.y; r[4 * i + 2] = v.z; r[4 * i + 3] = v.w;
  }

  float* op = out + (size_t)b * 9;

  float o[6];
  sim4h<0>(r, wt, &o[0]);
  sim4h<1>(r, wt, &o[2]);
  sim4h<2>(r, wt, &o[4]);
#pragma unroll
  for (int i = 0; i < 6; ++i) op[i] = o[i];

  float z[3];
  sim7h(r, wt + 12, z);
  op[6] = z[0]; op[7] = z[1]; op[8] = z[2];
}

// ---------------- launch ----------------------------------------------------

extern "C" void kernel_launch(void* const* d_in, const int* in_sizes, int n_in,
                              void* d_out, int out_size, void* d_ws, size_t ws_size,
                              hipStream_t stream) {
  const float* x  = (const float*)d_in[0];
  const float* wA = (const float*)d_in[1];
  const float* wB = (const float*)d_in[2];
  const float* wC = (const float*)d_in[3];
  const float* wD = (const float*)d_in[4];
  float* out = (float*)d_out;
  uint2* wt = (uint2*)d_ws;
  const int B = in_sizes[0] / 56;
  const int threads = 256;
  const int grid = (B + threads - 1) / threads;
  k_wt<<<1, 64, 0, stream>>>(wA, wB, wC, wD, wt);
  k_all<<<grid, threads, 0, stream>>>(x, wt, out, B);
}